// Round 1
// baseline (6213.990 us; speedup 1.0000x reference)
//
#include <hip/hip_runtime.h>

// Problem constants (from reference)
#define N_NODES 100000
#define N_EDGES 1600000
#define F_IN    128
#define H_DIM   128
#define C_DIM   16
#define N_REL   5

// ---------------------------------------------------------------------------
// cnt[n*R + r] = number of edges of type r into node n (as float), then 1/max(cnt,1)
// ---------------------------------------------------------------------------
__global__ void count_edges(const int* __restrict__ dst, const int* __restrict__ et,
                            float* __restrict__ cnt) {
    int e = blockIdx.x * blockDim.x + threadIdx.x;
    if (e >= N_EDGES) return;
    atomicAdd(&cnt[dst[e] * N_REL + et[e]], 1.0f);
}

__global__ void inv_count(float* __restrict__ cnt) {
    int i = blockIdx.x * blockDim.x + threadIdx.x;
    if (i >= N_NODES * N_REL) return;
    cnt[i] = 1.0f / fmaxf(cnt[i], 1.0f);
}

// ---------------------------------------------------------------------------
// Scatter messages of one relation: agg[dst] += ew * feat[src]
// 32 threads per edge, each handles one float4 (128 features = 32 x float4).
// ---------------------------------------------------------------------------
__global__ void scatter_rel(const float* __restrict__ feat,
                            const int* __restrict__ src, const int* __restrict__ dst,
                            const float* __restrict__ ew, const int* __restrict__ et,
                            int rel, float* __restrict__ agg) {
    int t = blockIdx.x * blockDim.x + threadIdx.x;
    int e = t >> 5;
    if (e >= N_EDGES) return;
    if (et[e] != rel) return;
    int q = t & 31;
    float w = ew[e];
    int s = src[e], d = dst[e];
    float4 v = reinterpret_cast<const float4*>(feat)[(size_t)s * 32 + q];
    float* outp = agg + (size_t)d * 128 + q * 4;
    atomicAdd(outp + 0, v.x * w);
    atomicAdd(outp + 1, v.y * w);
    atomicAdd(outp + 2, v.z * w);
    atomicAdd(outp + 3, v.w * w);
}

// ---------------------------------------------------------------------------
// C[n][BN] (+)= (scale[n] * A[n][0:128]) @ B[128][BN]  (+ bias, relu)
// BM=64 rows/block, K tiled 2x64, 256 threads.
// Layer1: BN=128, TM=8, TN=4 (acc 8x4). Layer2: BN=16, TM=4, TN=1.
// LDS: As 16KB + Bs (32KB | 4KB) -> 3 blocks/CU.
// ---------------------------------------------------------------------------
template<int BN, int TM, int TN, bool SCALE, bool ACCUM, bool BIAS, bool RELU>
__global__ __launch_bounds__(256) void gemm_k128(
    const float* __restrict__ A,      // [n_rows][128]
    const float* __restrict__ scale,  // pre-offset by rel; stride N_REL per row; null if !SCALE
    const float* __restrict__ B,      // [128][BN]
    const float* __restrict__ bias,   // [BN]
    float* __restrict__ C,            // [n_rows][BN]
    int n_rows)
{
    constexpr int BM = 64;
    __shared__ float As[BM][64];
    __shared__ float Bs[64][BN];
    const int tid = threadIdx.x;
    const int n0 = blockIdx.x * BM;
    constexpr int CG = BN / TN;
    const int cg = tid % CG, rg = tid / CG;
    const int r0 = rg * TM, c0 = cg * TN;

    float acc[TM][TN] = {};

    for (int kt = 0; kt < 2; ++kt) {
        // --- stage A chunk: BM x 64 (16 float4 per row) ---
        #pragma unroll
        for (int u = 0; u < (BM * 16) / 256; ++u) {
            int idx = tid + u * 256;
            int row = idx >> 4, c4 = idx & 15;
            float4 v = make_float4(0.f, 0.f, 0.f, 0.f);
            if (n0 + row < n_rows) {
                v = reinterpret_cast<const float4*>(A)[(size_t)(n0 + row) * 32 + kt * 16 + c4];
                if (SCALE) {
                    float sc = scale[(size_t)(n0 + row) * N_REL];
                    v.x *= sc; v.y *= sc; v.z *= sc; v.w *= sc;
                }
            }
            *reinterpret_cast<float4*>(&As[row][c4 * 4]) = v;
        }
        // --- stage B chunk: 64 x BN ---
        #pragma unroll
        for (int u = 0; u < (64 * BN / 4) / 256; ++u) {
            int idx = tid + u * 256;
            reinterpret_cast<float4*>(&Bs[0][0])[idx] =
                reinterpret_cast<const float4*>(B + (size_t)kt * 64 * BN)[idx];
        }
        __syncthreads();

        #pragma unroll 8
        for (int k = 0; k < 64; ++k) {
            float bv[TN];
            if constexpr (TN == 4) {
                float4 t4 = *reinterpret_cast<const float4*>(&Bs[k][c0]);
                bv[0] = t4.x; bv[1] = t4.y; bv[2] = t4.z; bv[3] = t4.w;
            } else {
                #pragma unroll
                for (int j = 0; j < TN; ++j) bv[j] = Bs[k][c0 + j];
            }
            #pragma unroll
            for (int i = 0; i < TM; ++i) {
                float a = As[r0 + i][k];
                #pragma unroll
                for (int j = 0; j < TN; ++j) acc[i][j] = fmaf(a, bv[j], acc[i][j]);
            }
        }
        __syncthreads();
    }

    #pragma unroll
    for (int i = 0; i < TM; ++i) {
        int row = n0 + r0 + i;
        if (row < n_rows) {
            float* cptr = C + (size_t)row * BN + c0;
            #pragma unroll
            for (int j = 0; j < TN; ++j) {
                float v = acc[i][j];
                if (ACCUM) v += cptr[j];
                if (BIAS)  v += bias[c0 + j];
                if (RELU)  v = fmaxf(v, 0.f);
                cptr[j] = v;
            }
        }
    }
}

// ---------------------------------------------------------------------------
// In-place log_softmax over rows of 16.
// ---------------------------------------------------------------------------
__global__ void log_softmax16(float* __restrict__ out) {
    int n = blockIdx.x * blockDim.x + threadIdx.x;
    if (n >= N_NODES) return;
    float4* p = reinterpret_cast<float4*>(out + (size_t)n * 16);
    float4 a = p[0], b = p[1], c = p[2], d = p[3];
    float m = a.x;
    m = fmaxf(m, a.y); m = fmaxf(m, a.z); m = fmaxf(m, a.w);
    m = fmaxf(m, b.x); m = fmaxf(m, b.y); m = fmaxf(m, b.z); m = fmaxf(m, b.w);
    m = fmaxf(m, c.x); m = fmaxf(m, c.y); m = fmaxf(m, c.z); m = fmaxf(m, c.w);
    m = fmaxf(m, d.x); m = fmaxf(m, d.y); m = fmaxf(m, d.z); m = fmaxf(m, d.w);
    float s = 0.f;
    s += expf(a.x - m) + expf(a.y - m) + expf(a.z - m) + expf(a.w - m);
    s += expf(b.x - m) + expf(b.y - m) + expf(b.z - m) + expf(b.w - m);
    s += expf(c.x - m) + expf(c.y - m) + expf(c.z - m) + expf(c.w - m);
    s += expf(d.x - m) + expf(d.y - m) + expf(d.z - m) + expf(d.w - m);
    float lse = m + logf(s);
    a.x -= lse; a.y -= lse; a.z -= lse; a.w -= lse;
    b.x -= lse; b.y -= lse; b.z -= lse; b.w -= lse;
    c.x -= lse; c.y -= lse; c.z -= lse; c.w -= lse;
    d.x -= lse; d.y -= lse; d.z -= lse; d.w -= lse;
    p[0] = a; p[1] = b; p[2] = c; p[3] = d;
}

// ---------------------------------------------------------------------------
extern "C" void kernel_launch(void* const* d_in, const int* in_sizes, int n_in,
                              void* d_out, int out_size, void* d_ws, size_t ws_size,
                              hipStream_t stream) {
    const float* x     = (const float*)d_in[0];
    const int*   ei    = (const int*)d_in[1];
    const int*   src   = ei;
    const int*   dst   = ei + N_EDGES;
    const float* ew    = (const float*)d_in[2];
    const int*   et    = (const int*)d_in[3];
    const float* W1    = (const float*)d_in[4];
    const float* root1 = (const float*)d_in[5];
    const float* b1    = (const float*)d_in[6];
    const float* W2    = (const float*)d_in[7];
    const float* root2 = (const float*)d_in[8];
    const float* b2    = (const float*)d_in[9];
    float* out = (float*)d_out;

    // workspace layout (total ~100 MiB)
    char* ws = (char*)d_ws;
    float* cnt = (float*)ws;                                    // N*R f32 = 2.0 MB
    float* agg = (float*)(ws + (2ull << 20));                   // N*128 f32 = 51.2 MB
    float* h   = (float*)(ws + (2ull << 20) + 51200000ull);     // N*128 f32 = 51.2 MB

    // --- degree counts (shared by both layers) ---
    hipMemsetAsync(cnt, 0, (size_t)N_NODES * N_REL * sizeof(float), stream);
    count_edges<<<(N_EDGES + 255) / 256, 256, 0, stream>>>(dst, et, cnt);
    inv_count<<<(N_NODES * N_REL + 255) / 256, 256, 0, stream>>>(cnt);

    const int sgrid = (N_EDGES * 32) / 256;           // 200000 blocks
    const int ggrid = (N_NODES + 63) / 64;            // 1563 blocks

    // --- layer 1: h = relu(sum_r mean_r(x) @ W1_r + x @ root1 + b1) ---
    for (int r = 0; r < N_REL; ++r) {
        hipMemsetAsync(agg, 0, (size_t)N_NODES * 128 * sizeof(float), stream);
        scatter_rel<<<sgrid, 256, 0, stream>>>(x, src, dst, ew, et, r, agg);
        if (r == 0)
            gemm_k128<128, 8, 4, true, false, false, false><<<ggrid, 256, 0, stream>>>(
                agg, cnt + r, W1 + (size_t)r * 128 * 128, nullptr, h, N_NODES);
        else
            gemm_k128<128, 8, 4, true, true, false, false><<<ggrid, 256, 0, stream>>>(
                agg, cnt + r, W1 + (size_t)r * 128 * 128, nullptr, h, N_NODES);
    }
    gemm_k128<128, 8, 4, false, true, true, true><<<ggrid, 256, 0, stream>>>(
        x, nullptr, root1, b1, h, N_NODES);

    // --- layer 2: out = sum_r mean_r(h) @ W2_r + h @ root2 + b2 ---
    for (int r = 0; r < N_REL; ++r) {
        hipMemsetAsync(agg, 0, (size_t)N_NODES * 128 * sizeof(float), stream);
        scatter_rel<<<sgrid, 256, 0, stream>>>(h, src, dst, ew, et, r, agg);
        if (r == 0)
            gemm_k128<16, 4, 1, true, false, false, false><<<ggrid, 256, 0, stream>>>(
                agg, cnt + r, W2 + (size_t)r * 128 * 16, nullptr, out, N_NODES);
        else
            gemm_k128<16, 4, 1, true, true, false, false><<<ggrid, 256, 0, stream>>>(
                agg, cnt + r, W2 + (size_t)r * 128 * 16, nullptr, out, N_NODES);
    }
    gemm_k128<16, 4, 1, false, true, true, false><<<ggrid, 256, 0, stream>>>(
        h, nullptr, root2, b2, out, N_NODES);

    log_softmax16<<<(N_NODES + 255) / 256, 256, 0, stream>>>(out);
}

// Round 2
// 1139.843 us; speedup vs baseline: 5.4516x; 5.4516x over previous
//
#include <hip/hip_runtime.h>

// Problem constants (from reference)
#define N_NODES 100000
#define N_EDGES 1600000
#define F_IN    128
#define H_DIM   128
#define C_DIM   16
#define N_REL   5
#define M_BUCKETS (N_NODES * N_REL)          // 500000 (dst,rel) buckets
#define SCAN_NB  ((M_BUCKETS + 1023) / 1024) // 489 scan blocks

// ---------------------------------------------------------------------------
// counts[n*R + r] = #edges of type r into node n (int histogram)
// ---------------------------------------------------------------------------
__global__ void count_edges(const int* __restrict__ dst, const int* __restrict__ et,
                            int* __restrict__ counts) {
    int e = blockIdx.x * blockDim.x + threadIdx.x;
    if (e >= N_EDGES) return;
    atomicAdd(&counts[dst[e] * N_REL + et[e]], 1);
}

// ---------------------------------------------------------------------------
// Hierarchical exclusive scan over counts[M_BUCKETS] -> offs (bucket starts)
// scan1: per-block (1024 elems, 256 thr x4) exclusive scan + block total
// scan2: single block scans the 489 block totals (exclusive)
// scan3: add block-total prefix
// ---------------------------------------------------------------------------
__global__ __launch_bounds__(256) void scan1(const int* __restrict__ counts,
                                             int* __restrict__ offs, int* __restrict__ tops) {
    __shared__ int lds[256];
    int tid = threadIdx.x;
    int base = blockIdx.x * 1024 + tid * 4;
    int v0 = (base + 0 < M_BUCKETS) ? counts[base + 0] : 0;
    int v1 = (base + 1 < M_BUCKETS) ? counts[base + 1] : 0;
    int v2 = (base + 2 < M_BUCKETS) ? counts[base + 2] : 0;
    int v3 = (base + 3 < M_BUCKETS) ? counts[base + 3] : 0;
    int s = v0 + v1 + v2 + v3;
    lds[tid] = s;
    __syncthreads();
    for (int d = 1; d < 256; d <<= 1) {
        int t = (tid >= d) ? lds[tid - d] : 0;
        __syncthreads();
        lds[tid] += t;
        __syncthreads();
    }
    int excl = lds[tid] - s;
    if (base + 0 < M_BUCKETS) offs[base + 0] = excl;
    excl += v0;
    if (base + 1 < M_BUCKETS) offs[base + 1] = excl;
    excl += v1;
    if (base + 2 < M_BUCKETS) offs[base + 2] = excl;
    excl += v2;
    if (base + 3 < M_BUCKETS) offs[base + 3] = excl;
    if (tid == 255) tops[blockIdx.x] = lds[255];
}

__global__ __launch_bounds__(512) void scan2(int* __restrict__ tops) {
    __shared__ int lds[512];
    int tid = threadIdx.x;
    int v = (tid < SCAN_NB) ? tops[tid] : 0;
    lds[tid] = v;
    __syncthreads();
    for (int d = 1; d < 512; d <<= 1) {
        int t = (tid >= d) ? lds[tid - d] : 0;
        __syncthreads();
        lds[tid] += t;
        __syncthreads();
    }
    if (tid < SCAN_NB) tops[tid] = lds[tid] - v;  // exclusive
}

__global__ void scan3(int* __restrict__ offs, const int* __restrict__ tops) {
    int i = blockIdx.x * blockDim.x + threadIdx.x;
    if (i >= M_BUCKETS) return;
    offs[i] += tops[i >> 10];
}

// ---------------------------------------------------------------------------
// Permute edges into bucket order. Bumps offs[b] from start->end; afterwards
// offs[b] == end(b) and start(b) == offs[b-1] (buckets are dense).
// ---------------------------------------------------------------------------
__global__ void fill_edges(const int* __restrict__ src, const int* __restrict__ dst,
                           const float* __restrict__ ew, const int* __restrict__ et,
                           int* __restrict__ offs,
                           int* __restrict__ ssrc, float* __restrict__ sw) {
    int e = blockIdx.x * blockDim.x + threadIdx.x;
    if (e >= N_EDGES) return;
    int b = dst[e] * N_REL + et[e];
    int pos = atomicAdd(&offs[b], 1);
    ssrc[pos] = src[e];
    sw[pos] = ew[e];
}

// ---------------------------------------------------------------------------
// Gather aggregation for one relation: one 64-lane wave per node bucket.
// agg[n][0:128] = (1/max(deg,1)) * sum_{e in bucket} w_e * feat[src_e]
// Lane i holds features [2i, 2i+1]; each edge is a coalesced 512B gather.
// ---------------------------------------------------------------------------
__global__ __launch_bounds__(256) void agg_rel(const float* __restrict__ feat,
                                               const int* __restrict__ offs,
                                               const int* __restrict__ ssrc,
                                               const float* __restrict__ sw,
                                               int rel, float* __restrict__ agg) {
    int gid = blockIdx.x * blockDim.x + threadIdx.x;
    int n = gid >> 6;
    if (n >= N_NODES) return;
    int lane = threadIdx.x & 63;
    int b = n * N_REL + rel;
    int start = (b == 0) ? 0 : offs[b - 1];
    int end = offs[b];
    float2 acc = make_float2(0.f, 0.f);
    const float2* f2 = reinterpret_cast<const float2*>(feat);
    for (int i = start; i < end; ++i) {
        int s = ssrc[i];
        float w = sw[i];
        float2 v = f2[(size_t)s * 64 + lane];
        acc.x = fmaf(w, v.x, acc.x);
        acc.y = fmaf(w, v.y, acc.y);
    }
    float inv = (end > start) ? 1.0f / (float)(end - start) : 0.f;
    reinterpret_cast<float2*>(agg)[(size_t)n * 64 + lane] =
        make_float2(acc.x * inv, acc.y * inv);
}

// ---------------------------------------------------------------------------
// C[n][BN] (+)= A[n][0:128] @ B[128][BN]  (+ bias, relu)
// BM=64 rows/block, K tiled 2x64, 256 threads.
// ---------------------------------------------------------------------------
template<int BN, int TM, int TN, bool ACCUM, bool BIAS, bool RELU>
__global__ __launch_bounds__(256) void gemm_k128(
    const float* __restrict__ A,      // [n_rows][128]
    const float* __restrict__ B,      // [128][BN]
    const float* __restrict__ bias,   // [BN]
    float* __restrict__ C,            // [n_rows][BN]
    int n_rows)
{
    constexpr int BM = 64;
    __shared__ float As[BM][64];
    __shared__ float Bs[64][BN];
    const int tid = threadIdx.x;
    const int n0 = blockIdx.x * BM;
    constexpr int CG = BN / TN;
    const int cg = tid % CG, rg = tid / CG;
    const int r0 = rg * TM, c0 = cg * TN;

    float acc[TM][TN] = {};

    for (int kt = 0; kt < 2; ++kt) {
        #pragma unroll
        for (int u = 0; u < (BM * 16) / 256; ++u) {
            int idx = tid + u * 256;
            int row = idx >> 4, c4 = idx & 15;
            float4 v = make_float4(0.f, 0.f, 0.f, 0.f);
            if (n0 + row < n_rows)
                v = reinterpret_cast<const float4*>(A)[(size_t)(n0 + row) * 32 + kt * 16 + c4];
            *reinterpret_cast<float4*>(&As[row][c4 * 4]) = v;
        }
        #pragma unroll
        for (int u = 0; u < (64 * BN / 4) / 256; ++u) {
            int idx = tid + u * 256;
            reinterpret_cast<float4*>(&Bs[0][0])[idx] =
                reinterpret_cast<const float4*>(B + (size_t)kt * 64 * BN)[idx];
        }
        __syncthreads();

        #pragma unroll 8
        for (int k = 0; k < 64; ++k) {
            float bv[TN];
            if constexpr (TN == 4) {
                float4 t4 = *reinterpret_cast<const float4*>(&Bs[k][c0]);
                bv[0] = t4.x; bv[1] = t4.y; bv[2] = t4.z; bv[3] = t4.w;
            } else {
                #pragma unroll
                for (int j = 0; j < TN; ++j) bv[j] = Bs[k][c0 + j];
            }
            #pragma unroll
            for (int i = 0; i < TM; ++i) {
                float a = As[r0 + i][k];
                #pragma unroll
                for (int j = 0; j < TN; ++j) acc[i][j] = fmaf(a, bv[j], acc[i][j]);
            }
        }
        __syncthreads();
    }

    #pragma unroll
    for (int i = 0; i < TM; ++i) {
        int row = n0 + r0 + i;
        if (row < n_rows) {
            float* cptr = C + (size_t)row * BN + c0;
            #pragma unroll
            for (int j = 0; j < TN; ++j) {
                float v = acc[i][j];
                if (ACCUM) v += cptr[j];
                if (BIAS)  v += bias[c0 + j];
                if (RELU)  v = fmaxf(v, 0.f);
                cptr[j] = v;
            }
        }
    }
}

// ---------------------------------------------------------------------------
// In-place log_softmax over rows of 16.
// ---------------------------------------------------------------------------
__global__ void log_softmax16(float* __restrict__ out) {
    int n = blockIdx.x * blockDim.x + threadIdx.x;
    if (n >= N_NODES) return;
    float4* p = reinterpret_cast<float4*>(out + (size_t)n * 16);
    float4 a = p[0], b = p[1], c = p[2], d = p[3];
    float m = a.x;
    m = fmaxf(m, a.y); m = fmaxf(m, a.z); m = fmaxf(m, a.w);
    m = fmaxf(m, b.x); m = fmaxf(m, b.y); m = fmaxf(m, b.z); m = fmaxf(m, b.w);
    m = fmaxf(m, c.x); m = fmaxf(m, c.y); m = fmaxf(m, c.z); m = fmaxf(m, c.w);
    m = fmaxf(m, d.x); m = fmaxf(m, d.y); m = fmaxf(m, d.z); m = fmaxf(m, d.w);
    float s = 0.f;
    s += expf(a.x - m) + expf(a.y - m) + expf(a.z - m) + expf(a.w - m);
    s += expf(b.x - m) + expf(b.y - m) + expf(b.z - m) + expf(b.w - m);
    s += expf(c.x - m) + expf(c.y - m) + expf(c.z - m) + expf(c.w - m);
    s += expf(d.x - m) + expf(d.y - m) + expf(d.z - m) + expf(d.w - m);
    float lse = m + logf(s);
    a.x -= lse; a.y -= lse; a.z -= lse; a.w -= lse;
    b.x -= lse; b.y -= lse; b.z -= lse; b.w -= lse;
    c.x -= lse; c.y -= lse; c.z -= lse; c.w -= lse;
    d.x -= lse; d.y -= lse; d.z -= lse; d.w -= lse;
    p[0] = a; p[1] = b; p[2] = c; p[3] = d;
}

// ---------------------------------------------------------------------------
extern "C" void kernel_launch(void* const* d_in, const int* in_sizes, int n_in,
                              void* d_out, int out_size, void* d_ws, size_t ws_size,
                              hipStream_t stream) {
    const float* x     = (const float*)d_in[0];
    const int*   ei    = (const int*)d_in[1];
    const int*   src   = ei;
    const int*   dst   = ei + N_EDGES;
    const float* ew    = (const float*)d_in[2];
    const int*   et    = (const int*)d_in[3];
    const float* W1    = (const float*)d_in[4];
    const float* root1 = (const float*)d_in[5];
    const float* b1    = (const float*)d_in[6];
    const float* W2    = (const float*)d_in[7];
    const float* root2 = (const float*)d_in[8];
    const float* b2    = (const float*)d_in[9];
    float* out = (float*)d_out;

    // workspace layout (~118 MiB)
    char* ws = (char*)d_ws;
    int*   offs  = (int*)ws;                                  // M_BUCKETS ints   (2.0 MB)
    int*   tops  = (int*)(ws + (2ull << 20));                 // 512 ints
    int*   ssrc  = (int*)(ws + (2ull << 20) + 4096);          // E ints           (6.4 MB)
    float* sw    = (float*)(ws + (9ull << 20));               // E floats         (6.4 MB)
    float* agg   = (float*)(ws + (16ull << 20));              // N*128 f32        (51.2 MB)
    float* h     = (float*)(ws + (16ull << 20) + 52428800ull);// N*128 f32        (51.2 MB)

    // --- build (dst,rel)-bucketed CSR once (shared by both layers) ---
    hipMemsetAsync(offs, 0, (size_t)M_BUCKETS * sizeof(int), stream);
    count_edges<<<(N_EDGES + 255) / 256, 256, 0, stream>>>(dst, et, offs);
    scan1<<<SCAN_NB, 256, 0, stream>>>(offs, offs, tops);   // in-place ok: block-local
    scan2<<<1, 512, 0, stream>>>(tops);
    scan3<<<(M_BUCKETS + 255) / 256, 256, 0, stream>>>(offs, tops);
    fill_edges<<<(N_EDGES + 255) / 256, 256, 0, stream>>>(src, dst, ew, et, offs, ssrc, sw);

    const int agrid = (N_NODES * 64 + 255) / 256;   // one wave per node
    const int ggrid = (N_NODES + 63) / 64;

    // --- layer 1: h = relu(sum_r mean_r(x) @ W1_r + x @ root1 + b1) ---
    for (int r = 0; r < N_REL; ++r) {
        agg_rel<<<agrid, 256, 0, stream>>>(x, offs, ssrc, sw, r, agg);
        if (r == 0)
            gemm_k128<128, 8, 4, false, false, false><<<ggrid, 256, 0, stream>>>(
                agg, W1 + (size_t)r * 128 * 128, nullptr, h, N_NODES);
        else
            gemm_k128<128, 8, 4, true, false, false><<<ggrid, 256, 0, stream>>>(
                agg, W1 + (size_t)r * 128 * 128, nullptr, h, N_NODES);
    }
    gemm_k128<128, 8, 4, true, true, true><<<ggrid, 256, 0, stream>>>(
        x, root1, b1, h, N_NODES);

    // --- layer 2: out = sum_r mean_r(h) @ W2_r + h @ root2 + b2 ---
    for (int r = 0; r < N_REL; ++r) {
        agg_rel<<<agrid, 256, 0, stream>>>(h, offs, ssrc, sw, r, agg);
        if (r == 0)
            gemm_k128<16, 4, 1, false, false, false><<<ggrid, 256, 0, stream>>>(
                agg, W2 + (size_t)r * 128 * 16, nullptr, out, N_NODES);
        else
            gemm_k128<16, 4, 1, true, false, false><<<ggrid, 256, 0, stream>>>(
                agg, W2 + (size_t)r * 128 * 16, nullptr, out, N_NODES);
    }
    gemm_k128<16, 4, 1, true, true, false><<<ggrid, 256, 0, stream>>>(
        h, root2, b2, out, N_NODES);

    log_softmax16<<<(N_NODES + 255) / 256, 256, 0, stream>>>(out);
}

// Round 3
// 966.416 us; speedup vs baseline: 6.4299x; 1.1795x over previous
//
#include <hip/hip_runtime.h>

// Problem constants (from reference)
#define N_NODES 100000
#define N_EDGES 1600000
#define N_REL   5
#define M_BUCKETS (N_NODES * N_REL)          // 500000 (dst,rel) buckets
#define SCAN_NB  ((M_BUCKETS + 1023) / 1024) // 489 scan blocks

using bf16x8 = __attribute__((ext_vector_type(8))) short;
using f32x4  = __attribute__((ext_vector_type(4))) float;

__device__ __forceinline__ unsigned short f2bf(float f) {
    unsigned int u = __float_as_uint(f);
    u += 0x7fffu + ((u >> 16) & 1u);          // RNE
    return (unsigned short)(u >> 16);
}
__device__ __forceinline__ float bflo(unsigned int p) { return __uint_as_float(p << 16); }
__device__ __forceinline__ float bfhi(unsigned int p) { return __uint_as_float(p & 0xffff0000u); }

// ---------------------------------------------------------------------------
// CSR build: histogram -> hierarchical exclusive scan -> permute
// ---------------------------------------------------------------------------
__global__ void count_edges(const int* __restrict__ dst, const int* __restrict__ et,
                            int* __restrict__ counts) {
    int e = blockIdx.x * blockDim.x + threadIdx.x;
    if (e >= N_EDGES) return;
    atomicAdd(&counts[dst[e] * N_REL + et[e]], 1);
}

__global__ __launch_bounds__(256) void scan1(const int* __restrict__ counts,
                                             int* __restrict__ offs, int* __restrict__ tops) {
    __shared__ int lds[256];
    int tid = threadIdx.x;
    int base = blockIdx.x * 1024 + tid * 4;
    int v0 = (base + 0 < M_BUCKETS) ? counts[base + 0] : 0;
    int v1 = (base + 1 < M_BUCKETS) ? counts[base + 1] : 0;
    int v2 = (base + 2 < M_BUCKETS) ? counts[base + 2] : 0;
    int v3 = (base + 3 < M_BUCKETS) ? counts[base + 3] : 0;
    int s = v0 + v1 + v2 + v3;
    lds[tid] = s;
    __syncthreads();
    for (int d = 1; d < 256; d <<= 1) {
        int t = (tid >= d) ? lds[tid - d] : 0;
        __syncthreads();
        lds[tid] += t;
        __syncthreads();
    }
    int excl = lds[tid] - s;
    if (base + 0 < M_BUCKETS) offs[base + 0] = excl;
    excl += v0;
    if (base + 1 < M_BUCKETS) offs[base + 1] = excl;
    excl += v1;
    if (base + 2 < M_BUCKETS) offs[base + 2] = excl;
    excl += v2;
    if (base + 3 < M_BUCKETS) offs[base + 3] = excl;
    if (tid == 255) tops[blockIdx.x] = lds[255];
}

__global__ __launch_bounds__(512) void scan2(int* __restrict__ tops) {
    __shared__ int lds[512];
    int tid = threadIdx.x;
    int v = (tid < SCAN_NB) ? tops[tid] : 0;
    lds[tid] = v;
    __syncthreads();
    for (int d = 1; d < 512; d <<= 1) {
        int t = (tid >= d) ? lds[tid - d] : 0;
        __syncthreads();
        lds[tid] += t;
        __syncthreads();
    }
    if (tid < SCAN_NB) tops[tid] = lds[tid] - v;  // exclusive
}

__global__ void scan3(int* __restrict__ offs, const int* __restrict__ tops) {
    int i = blockIdx.x * blockDim.x + threadIdx.x;
    if (i >= M_BUCKETS) return;
    offs[i] += tops[i >> 10];
}

// Permute edges into bucket order: one combined 8B record per edge.
__global__ void fill_edges(const int* __restrict__ src, const int* __restrict__ dst,
                           const float* __restrict__ ew, const int* __restrict__ et,
                           int* __restrict__ offs, int2* __restrict__ edges) {
    int e = blockIdx.x * blockDim.x + threadIdx.x;
    if (e >= N_EDGES) return;
    int b = dst[e] * N_REL + et[e];
    int pos = atomicAdd(&offs[b], 1);
    edges[pos] = make_int2(src[e], __float_as_int(ew[e]));
}

// ---------------------------------------------------------------------------
// Precision conversions (once per launch)
// ---------------------------------------------------------------------------
__global__ void cvt_feat(const float* __restrict__ x, ushort* __restrict__ xh) {
    int i = blockIdx.x * blockDim.x + threadIdx.x;   // float4 index
    if (i >= (N_NODES * 128) / 4) return;
    float4 v = reinterpret_cast<const float4*>(x)[i];
    ushort4 o;
    o.x = f2bf(v.x); o.y = f2bf(v.y); o.z = f2bf(v.z); o.w = f2bf(v.w);
    reinterpret_cast<ushort4*>(xh)[i] = o;
}

// W[b][K=128][NN] f32  ->  Wt[b][NN][128] bf16  (batch = blockIdx.y)
__global__ void cvt_w_t(const float* __restrict__ W, ushort* __restrict__ Wt, int NN) {
    const float* Wb = W + (size_t)blockIdx.y * 128 * NN;
    ushort* Wtb = Wt + (size_t)blockIdx.y * 128 * NN;
    int i = blockIdx.x * blockDim.x + threadIdx.x;   // output index o*128 + k
    if (i >= 128 * NN) return;
    int o = i >> 7, k = i & 127;
    Wtb[i] = f2bf(Wb[k * NN + o]);
}

// ---------------------------------------------------------------------------
// Fused per-layer kernel: block = 64 nodes, 256 threads (4 waves).
// Phases r=0..4: wave-per-node gather-mean of relation r into LDS As (bf16,
// XOR-swizzled), then MFMA vs Wt_r tile. Phase 5: own features vs root.
// Accumulate all phases in f32 acc frags; epilogue bias (+relu) -> out.
// BN=128 (layer1, bf16 out) or BN=16 (layer2, f32 out).
// ---------------------------------------------------------------------------
template<int BN, bool RELU, bool F32OUT>
__global__ __launch_bounds__(256) void fused_layer(
    const ushort* __restrict__ feat,   // bf16 [N][128]
    const int2*  __restrict__ edges,   // bucket-sorted (src, weight-bits)
    const int*   __restrict__ offs,    // bucket end offsets (dense)
    const ushort* __restrict__ Wt,     // bf16 [R][BN][128]  (W^T)
    const ushort* __restrict__ roott,  // bf16 [BN][128]     (root^T)
    const float* __restrict__ bias,    // f32 [BN]
    void* __restrict__ outp)           // F32OUT ? f32 [N][16] : bf16 [N][128]
{
    __shared__ ushort As[64 * 128];    // 16 KB, swizzled
    __shared__ ushort Bs[BN * 128];    // 32 KB | 4 KB, swizzled

    const int tid  = threadIdx.x;
    const int wave = tid >> 6, lane = tid & 63;
    const int n0 = blockIdx.x * 64;

    constexpr int MF = (BN == 128) ? 4 : 1;   // 16-row frags per wave
    constexpr int NF = (BN == 128) ? 2 : 1;   // 16-col frags per wave
    const int wr0 = (BN == 128) ? 0 : wave * 16;   // wave row base
    const int wc0 = (BN == 128) ? wave * 32 : 0;   // wave col base

    f32x4 acc[MF][NF] = {};

    for (int r = 0; r < 6; ++r) {
        // ---- phase aggregation: wave handles rows [wave*16, wave*16+16) ----
        for (int ii = 0; ii < 16; ++ii) {
            int row = wave * 16 + ii;
            int n = n0 + row;
            float ax = 0.f, ay = 0.f;
            if (n < N_NODES) {
                if (r < N_REL) {
                    int b = n * N_REL + r;
                    int s0 = (b == 0) ? 0 : offs[b - 1];
                    int e0 = offs[b];
                    for (int i = s0; i < e0; ++i) {
                        int2 ed = edges[i];
                        float w = __int_as_float(ed.y);
                        unsigned int p =
                            reinterpret_cast<const unsigned int*>(feat)[(size_t)ed.x * 64 + lane];
                        ax = fmaf(w, bflo(p), ax);
                        ay = fmaf(w, bfhi(p), ay);
                    }
                    float inv = (e0 > s0) ? 1.0f / (float)(e0 - s0) : 0.f;
                    ax *= inv; ay *= inv;
                } else {  // root phase: own feature row
                    unsigned int p =
                        reinterpret_cast<const unsigned int*>(feat)[(size_t)n * 64 + lane];
                    ax = bflo(p); ay = bfhi(p);
                }
            }
            unsigned int packed = (unsigned int)f2bf(ax) | ((unsigned int)f2bf(ay) << 16);
            int byte = (row * 256 + lane * 4) ^ ((row & 7) << 4);
            *reinterpret_cast<unsigned int*>(reinterpret_cast<char*>(As) + byte) = packed;
        }

        // ---- stage Wt tile (BN x 128 bf16) into Bs, swizzled ----
        const ushort* wsrc = (r < N_REL) ? (Wt + (size_t)r * BN * 128) : roott;
        #pragma unroll
        for (int c = tid; c < BN * 16; c += 256) {   // 16B chunks
            int brow = c >> 4, col16 = c & 15;
            int byte = (brow * 256 + col16 * 16) ^ ((brow & 7) << 4);
            *reinterpret_cast<float4*>(reinterpret_cast<char*>(Bs) + byte) =
                reinterpret_cast<const float4*>(wsrc)[c];
        }
        __syncthreads();

        // ---- MFMA over K=128 (4 steps of 32) ----
        #pragma unroll
        for (int ks = 0; ks < 4; ++ks) {
            int kb = ks * 64 + (lane >> 4) * 16;   // byte offset within row
            bf16x8 af[MF], bfr[NF];
            #pragma unroll
            for (int m = 0; m < MF; ++m) {
                int row = wr0 + m * 16 + (lane & 15);
                int byte = (row * 256 + kb) ^ ((row & 7) << 4);
                af[m] = *reinterpret_cast<const bf16x8*>(
                    reinterpret_cast<const char*>(As) + byte);
            }
            #pragma unroll
            for (int nn = 0; nn < NF; ++nn) {
                int row = wc0 + nn * 16 + (lane & 15);
                int byte = (row * 256 + kb) ^ ((row & 7) << 4);
                bfr[nn] = *reinterpret_cast<const bf16x8*>(
                    reinterpret_cast<const char*>(Bs) + byte);
            }
            #pragma unroll
            for (int m = 0; m < MF; ++m)
                #pragma unroll
                for (int nn = 0; nn < NF; ++nn)
                    acc[m][nn] = __builtin_amdgcn_mfma_f32_16x16x32_bf16(
                        af[m], bfr[nn], acc[m][nn], 0, 0, 0);
        }
        __syncthreads();
    }

    // ---- epilogue: D col=lane&15, row=(lane>>4)*4+q ----
    const int col = lane & 15;
    #pragma unroll
    for (int m = 0; m < MF; ++m) {
        #pragma unroll
        for (int nn = 0; nn < NF; ++nn) {
            int c = wc0 + nn * 16 + col;
            #pragma unroll
            for (int q = 0; q < 4; ++q) {
                int n = n0 + wr0 + m * 16 + (lane >> 4) * 4 + q;
                if (n < N_NODES) {
                    float v = acc[m][nn][q] + bias[c];
                    if (RELU) v = fmaxf(v, 0.f);
                    if (F32OUT)
                        reinterpret_cast<float*>(outp)[(size_t)n * 16 + c] = v;
                    else
                        reinterpret_cast<ushort*>(outp)[(size_t)n * 128 + c] = f2bf(v);
                }
            }
        }
    }
}

// ---------------------------------------------------------------------------
// In-place log_softmax over rows of 16.
// ---------------------------------------------------------------------------
__global__ void log_softmax16(float* __restrict__ out) {
    int n = blockIdx.x * blockDim.x + threadIdx.x;
    if (n >= N_NODES) return;
    float4* p = reinterpret_cast<float4*>(out + (size_t)n * 16);
    float4 a = p[0], b = p[1], c = p[2], d = p[3];
    float m = a.x;
    m = fmaxf(m, a.y); m = fmaxf(m, a.z); m = fmaxf(m, a.w);
    m = fmaxf(m, b.x); m = fmaxf(m, b.y); m = fmaxf(m, b.z); m = fmaxf(m, b.w);
    m = fmaxf(m, c.x); m = fmaxf(m, c.y); m = fmaxf(m, c.z); m = fmaxf(m, c.w);
    m = fmaxf(m, d.x); m = fmaxf(m, d.y); m = fmaxf(m, d.z); m = fmaxf(m, d.w);
    float s = 0.f;
    s += expf(a.x - m) + expf(a.y - m) + expf(a.z - m) + expf(a.w - m);
    s += expf(b.x - m) + expf(b.y - m) + expf(b.z - m) + expf(b.w - m);
    s += expf(c.x - m) + expf(c.y - m) + expf(c.z - m) + expf(c.w - m);
    s += expf(d.x - m) + expf(d.y - m) + expf(d.z - m) + expf(d.w - m);
    float lse = m + logf(s);
    a.x -= lse; a.y -= lse; a.z -= lse; a.w -= lse;
    b.x -= lse; b.y -= lse; b.z -= lse; b.w -= lse;
    c.x -= lse; c.y -= lse; c.z -= lse; c.w -= lse;
    d.x -= lse; d.y -= lse; d.z -= lse; d.w -= lse;
    p[0] = a; p[1] = b; p[2] = c; p[3] = d;
}

// ---------------------------------------------------------------------------
extern "C" void kernel_launch(void* const* d_in, const int* in_sizes, int n_in,
                              void* d_out, int out_size, void* d_ws, size_t ws_size,
                              hipStream_t stream) {
    const float* x     = (const float*)d_in[0];
    const int*   ei    = (const int*)d_in[1];
    const int*   src   = ei;
    const int*   dst   = ei + N_EDGES;
    const float* ew    = (const float*)d_in[2];
    const int*   et    = (const int*)d_in[3];
    const float* W1    = (const float*)d_in[4];
    const float* root1 = (const float*)d_in[5];
    const float* b1    = (const float*)d_in[6];
    const float* W2    = (const float*)d_in[7];
    const float* root2 = (const float*)d_in[8];
    const float* b2    = (const float*)d_in[9];
    float* out = (float*)d_out;

    // workspace layout (~66.3 MiB)
    char* ws = (char*)d_ws;
    int*    offs   = (int*)ws;                          // 2,000,000 B
    int*    tops   = (int*)(ws + 2000000);              // ~2 KB
    int2*   edges  = (int2*)(ws + 2004096);             // 12.8 MB
    ushort* xh     = (ushort*)(ws + 14804096);          // 25.6 MB
    ushort* hh     = (ushort*)(ws + 40404096);          // 25.6 MB
    ushort* W1t    = (ushort*)(ws + 66004096);          // 163,840 B
    ushort* root1t = (ushort*)(ws + 66167936);          // 32,768 B
    ushort* W2t    = (ushort*)(ws + 66200704);          // 20,480 B
    ushort* root2t = (ushort*)(ws + 66221184);          // 4,096 B

    // --- precision conversions (small, once) ---
    cvt_feat<<<((N_NODES * 128 / 4) + 255) / 256, 256, 0, stream>>>(x, xh);
    cvt_w_t<<<dim3((128 * 128 + 255) / 256, N_REL), 256, 0, stream>>>(W1, W1t, 128);
    cvt_w_t<<<dim3((128 * 128 + 255) / 256, 1), 256, 0, stream>>>(root1, root1t, 128);
    cvt_w_t<<<dim3((128 * 16 + 255) / 256, N_REL), 256, 0, stream>>>(W2, W2t, 16);
    cvt_w_t<<<dim3((128 * 16 + 255) / 256, 1), 256, 0, stream>>>(root2, root2t, 16);

    // --- build (dst,rel)-bucketed CSR once (shared by both layers) ---
    hipMemsetAsync(offs, 0, (size_t)M_BUCKETS * sizeof(int), stream);
    count_edges<<<(N_EDGES + 255) / 256, 256, 0, stream>>>(dst, et, offs);
    scan1<<<SCAN_NB, 256, 0, stream>>>(offs, offs, tops);
    scan2<<<1, 512, 0, stream>>>(tops);
    scan3<<<(M_BUCKETS + 255) / 256, 256, 0, stream>>>(offs, tops);
    fill_edges<<<(N_EDGES + 255) / 256, 256, 0, stream>>>(src, dst, ew, et, offs, edges);

    const int lgrid = (N_NODES + 63) / 64;   // 1563

    // --- layer 1: hh = bf16(relu(sum_r mean_r(xh)@W1_r + xh@root1 + b1)) ---
    fused_layer<128, true, false><<<lgrid, 256, 0, stream>>>(
        xh, edges, offs, W1t, root1t, b1, hh);

    // --- layer 2: out = sum_r mean_r(hh)@W2_r + hh@root2 + b2 ---
    fused_layer<16, false, true><<<lgrid, 256, 0, stream>>>(
        hh, edges, offs, W2t, root2t, b2, out);

    log_softmax16<<<(N_NODES + 255) / 256, 256, 0, stream>>>(out);
}

// Round 4
// 516.753 us; speedup vs baseline: 12.0251x; 1.8702x over previous
//
#include <hip/hip_runtime.h>

// Problem constants (from reference)
#define N_NODES 100000
#define N_EDGES 1600000
#define N_REL   5
#define M_BUCKETS (N_NODES * N_REL)          // 500000 (dst,rel) buckets
#define SCAN_NB  ((M_BUCKETS + 1023) / 1024) // 489 scan blocks
#define CHUNK   25000                        // nodes per processing chunk
#define NCHUNK  4

using bf16x8 = __attribute__((ext_vector_type(8))) short;
using f32x4  = __attribute__((ext_vector_type(4))) float;

__device__ __forceinline__ unsigned short f2bf(float f) {
    unsigned int u = __float_as_uint(f);
    u += 0x7fffu + ((u >> 16) & 1u);          // RNE
    return (unsigned short)(u >> 16);
}
__device__ __forceinline__ float bflo(unsigned int p) { return __uint_as_float(p << 16); }
__device__ __forceinline__ float bfhi(unsigned int p) { return __uint_as_float(p & 0xffff0000u); }

// ---------------------------------------------------------------------------
// CSR build: histogram -> hierarchical exclusive scan -> permute
// ---------------------------------------------------------------------------
__global__ void count_edges(const int* __restrict__ dst, const int* __restrict__ et,
                            int* __restrict__ counts) {
    int e = blockIdx.x * blockDim.x + threadIdx.x;
    if (e >= N_EDGES) return;
    atomicAdd(&counts[dst[e] * N_REL + et[e]], 1);
}

__global__ __launch_bounds__(256) void scan1(const int* __restrict__ counts,
                                             int* __restrict__ offs, int* __restrict__ tops) {
    __shared__ int lds[256];
    int tid = threadIdx.x;
    int base = blockIdx.x * 1024 + tid * 4;
    int v0 = (base + 0 < M_BUCKETS) ? counts[base + 0] : 0;
    int v1 = (base + 1 < M_BUCKETS) ? counts[base + 1] : 0;
    int v2 = (base + 2 < M_BUCKETS) ? counts[base + 2] : 0;
    int v3 = (base + 3 < M_BUCKETS) ? counts[base + 3] : 0;
    int s = v0 + v1 + v2 + v3;
    lds[tid] = s;
    __syncthreads();
    for (int d = 1; d < 256; d <<= 1) {
        int t = (tid >= d) ? lds[tid - d] : 0;
        __syncthreads();
        lds[tid] += t;
        __syncthreads();
    }
    int excl = lds[tid] - s;
    if (base + 0 < M_BUCKETS) offs[base + 0] = excl;
    excl += v0;
    if (base + 1 < M_BUCKETS) offs[base + 1] = excl;
    excl += v1;
    if (base + 2 < M_BUCKETS) offs[base + 2] = excl;
    excl += v2;
    if (base + 3 < M_BUCKETS) offs[base + 3] = excl;
    if (tid == 255) tops[blockIdx.x] = lds[255];
}

__global__ __launch_bounds__(512) void scan2(int* __restrict__ tops) {
    __shared__ int lds[512];
    int tid = threadIdx.x;
    int v = (tid < SCAN_NB) ? tops[tid] : 0;
    lds[tid] = v;
    __syncthreads();
    for (int d = 1; d < 512; d <<= 1) {
        int t = (tid >= d) ? lds[tid - d] : 0;
        __syncthreads();
        lds[tid] += t;
        __syncthreads();
    }
    if (tid < SCAN_NB) tops[tid] = lds[tid] - v;  // exclusive
}

__global__ void scan3(int* __restrict__ offs, const int* __restrict__ tops) {
    int i = blockIdx.x * blockDim.x + threadIdx.x;
    if (i >= M_BUCKETS) return;
    offs[i] += tops[i >> 10];
}

// Permute edges into bucket order. Record packs (src | rel<<17, w/deg).
// After this kernel offs[b] == end(b); start(b) == offs[b-1] (dense buckets).
__global__ void fill_edges(const int* __restrict__ src, const int* __restrict__ dst,
                           const float* __restrict__ ew, const int* __restrict__ et,
                           const int* __restrict__ counts,
                           int* __restrict__ offs, int2* __restrict__ edges) {
    int e = blockIdx.x * blockDim.x + threadIdx.x;
    if (e >= N_EDGES) return;
    int r = et[e];
    int b = dst[e] * N_REL + r;
    int pos = atomicAdd(&offs[b], 1);
    float wp = ew[e] / (float)counts[b];     // counts[b] >= 1 here
    edges[pos] = make_int2(src[e] | (r << 17), __float_as_int(wp));
}

// ---------------------------------------------------------------------------
// Precision conversions (once per launch)
// ---------------------------------------------------------------------------
__global__ void cvt_feat(const float* __restrict__ x, ushort* __restrict__ xh) {
    int i = blockIdx.x * blockDim.x + threadIdx.x;   // float4 index
    if (i >= (N_NODES * 128) / 4) return;
    float4 v = reinterpret_cast<const float4*>(x)[i];
    ushort4 o;
    o.x = f2bf(v.x); o.y = f2bf(v.y); o.z = f2bf(v.z); o.w = f2bf(v.w);
    reinterpret_cast<ushort4*>(xh)[i] = o;
}

// Stack [root; W_0..W_4] transposed: Wt[o][seg*128+k], seg0=root, seg r+1=W_r.
// W: [R][128][NN] f32, root: [128][NN] f32. grid: dim3(3, NN), 256 thr.
__global__ void cvt_wstack(const float* __restrict__ W, const float* __restrict__ root,
                           ushort* __restrict__ Wt, int NN) {
    int t = blockIdx.x * blockDim.x + threadIdx.x;   // 0..767
    int o = blockIdx.y;
    int seg = t >> 7, k = t & 127;
    float v = (seg == 0) ? root[k * NN + o] : W[(size_t)(seg - 1) * 128 * NN + k * NN + o];
    Wt[(size_t)o * 768 + t] = f2bf(v);
}

// ---------------------------------------------------------------------------
// Gather-aggregate, one wave per node, all relations in one pass.
// Writes A[n-node0][768] bf16 = [own(128) | mean_r0(128) | ... | mean_r4(128)].
// Edge records for a node's 5 buckets are CONTIGUOUS: batch-load up to 64
// lane-parallel, broadcast via readlane (wave-uniform indices -> SGPRs),
// 8-deep unrolled feature gathers for ILP. w/deg pre-folded in record.
// ---------------------------------------------------------------------------
__global__ __launch_bounds__(256) void gather_all(
    const ushort* __restrict__ feat,   // bf16 [N][128]
    const int2* __restrict__ edges,
    const int* __restrict__ offs,
    ushort* __restrict__ A,            // [>=CHUNK][768] bf16
    int node0) {
    int n = __builtin_amdgcn_readfirstlane(node0 + blockIdx.x * 4 + (threadIdx.x >> 6));
    int lane = threadIdx.x & 63;
    int b0 = n * N_REL;
    int start = (b0 == 0) ? 0 : offs[b0 - 1];
    int end = offs[b0 + 4];
    const unsigned int* fp = reinterpret_cast<const unsigned int*>(feat);

    unsigned int own = fp[(size_t)n * 64 + lane];
    float a0x = 0.f, a0y = 0.f, a1x = 0.f, a1y = 0.f, a2x = 0.f, a2y = 0.f;
    float a3x = 0.f, a3y = 0.f, a4x = 0.f, a4y = 0.f;

    for (int base = start; base < end; base += 64) {
        int idx = base + lane;
        int2 er = (idx < end) ? edges[idx] : make_int2(0, 0);  // pad: w=0, rel=0, src=0
        int cnt = end - base; if (cnt > 64) cnt = 64;
        int cnt8 = (cnt + 7) & ~7;
        for (int e = 0; e < cnt8; e += 8) {
            #pragma unroll
            for (int j = 0; j < 8; ++j) {
                int meta = __builtin_amdgcn_readlane(er.x, e + j);
                float w = __uint_as_float(__builtin_amdgcn_readlane(er.y, e + j));
                int s = meta & 0x1FFFF;
                int rel = meta >> 17;
                unsigned int p = fp[(size_t)s * 64 + lane];
                float lo = bflo(p), hi = bfhi(p);
                float w0 = (rel == 0) ? w : 0.f;
                float w1 = (rel == 1) ? w : 0.f;
                float w2 = (rel == 2) ? w : 0.f;
                float w3 = (rel == 3) ? w : 0.f;
                float w4 = (rel == 4) ? w : 0.f;
                a0x = fmaf(w0, lo, a0x); a0y = fmaf(w0, hi, a0y);
                a1x = fmaf(w1, lo, a1x); a1y = fmaf(w1, hi, a1y);
                a2x = fmaf(w2, lo, a2x); a2y = fmaf(w2, hi, a2y);
                a3x = fmaf(w3, lo, a3x); a3y = fmaf(w3, hi, a3y);
                a4x = fmaf(w4, lo, a4x); a4y = fmaf(w4, hi, a4y);
            }
        }
    }

    unsigned int* Ap = reinterpret_cast<unsigned int*>(A) + (size_t)(n - node0) * 384;
    Ap[lane] = own;
    Ap[64 * 1 + lane] = (unsigned int)f2bf(a0x) | ((unsigned int)f2bf(a0y) << 16);
    Ap[64 * 2 + lane] = (unsigned int)f2bf(a1x) | ((unsigned int)f2bf(a1y) << 16);
    Ap[64 * 3 + lane] = (unsigned int)f2bf(a2x) | ((unsigned int)f2bf(a2y) << 16);
    Ap[64 * 4 + lane] = (unsigned int)f2bf(a3x) | ((unsigned int)f2bf(a3y) << 16);
    Ap[64 * 5 + lane] = (unsigned int)f2bf(a4x) | ((unsigned int)f2bf(a4y) << 16);
}

// ---------------------------------------------------------------------------
// GEMM: out[row][BN] = A[row][768] @ Wt[BN][768]^T + bias (+relu)
// 128-row tiles, K stepped by 64, XOR-swizzled LDS, mfma_f32_16x16x32_bf16.
// BN=128: 4 waves 2x2, 64x64/wave. BN=16: 4 waves stacked, 32x16/wave.
// ---------------------------------------------------------------------------
template<int BN, bool RELU, bool F32OUT>
__global__ __launch_bounds__(256) void gemm768(
    const ushort* __restrict__ A,    // chunk-local [rows][768] bf16
    const ushort* __restrict__ Wt,   // [BN][768] bf16
    const float* __restrict__ bias,  // [BN]
    void* __restrict__ outp,         // bf16 [N][BN] or f32 [N][BN]
    int row0, int nrows) {           // global row base, valid rows in chunk
    __shared__ ushort As[128 * 64];          // 16 KB
    __shared__ ushort Bs[BN * 64];           // 16 KB | 2 KB
    const int tid = threadIdx.x, lane = tid & 63, wave = tid >> 6;
    const int m0 = blockIdx.x * 128;         // chunk-local row base

    constexpr int MF = (BN == 128) ? 4 : 2;
    constexpr int NF = (BN == 128) ? 4 : 1;
    const int wr0 = (BN == 128) ? (wave >> 1) * 64 : wave * 32;
    const int wc0 = (BN == 128) ? (wave & 1) * 64 : 0;

    f32x4 acc[MF][NF] = {};

    for (int ks = 0; ks < 12; ++ks) {
        // stage As: 1024 x 16B chunks (rows may over-read chunk pad; guarded at store)
        #pragma unroll
        for (int u = 0; u < 4; ++u) {
            int idx = tid + u * 256;
            int row = idx >> 3, slot = idx & 7;
            float4 v = *reinterpret_cast<const float4*>(
                A + (size_t)(m0 + row) * 768 + ks * 64 + slot * 8);
            int byte = row * 128 + ((slot ^ (row & 7)) << 4);
            *reinterpret_cast<float4*>(reinterpret_cast<char*>(As) + byte) = v;
        }
        // stage Bs: BN*8 x 16B chunks
        constexpr int BCH = BN * 8;
        #pragma unroll
        for (int u = 0; u < (BCH + 255) / 256; ++u) {
            int idx = tid + u * 256;
            if ((BCH % 256) && idx >= BCH) break;
            int row = idx >> 3, slot = idx & 7;
            float4 v = *reinterpret_cast<const float4*>(
                Wt + (size_t)row * 768 + ks * 64 + slot * 8);
            int byte = row * 128 + ((slot ^ (row & 7)) << 4);
            *reinterpret_cast<float4*>(reinterpret_cast<char*>(Bs) + byte) = v;
        }
        __syncthreads();

        #pragma unroll
        for (int kh = 0; kh < 2; ++kh) {
            bf16x8 af[MF], bfr[NF];
            #pragma unroll
            for (int m = 0; m < MF; ++m) {
                int row = wr0 + m * 16 + (lane & 15);
                int slot = kh * 4 + (lane >> 4);
                int byte = row * 128 + ((slot ^ (row & 7)) << 4);
                af[m] = *reinterpret_cast<const bf16x8*>(
                    reinterpret_cast<const char*>(As) + byte);
            }
            #pragma unroll
            for (int nn = 0; nn < NF; ++nn) {
                int row = wc0 + nn * 16 + (lane & 15);
                int slot = kh * 4 + (lane >> 4);
                int byte = row * 128 + ((slot ^ (row & 7)) << 4);
                bfr[nn] = *reinterpret_cast<const bf16x8*>(
                    reinterpret_cast<const char*>(Bs) + byte);
            }
            #pragma unroll
            for (int m = 0; m < MF; ++m)
                #pragma unroll
                for (int nn = 0; nn < NF; ++nn)
                    acc[m][nn] = __builtin_amdgcn_mfma_f32_16x16x32_bf16(
                        af[m], bfr[nn], acc[m][nn], 0, 0, 0);
        }
        __syncthreads();
    }

    // epilogue: D col=lane&15, row=(lane>>4)*4+q
    #pragma unroll
    for (int m = 0; m < MF; ++m) {
        int rloc = wr0 + m * 16 + (lane >> 4) * 4;
        #pragma unroll
        for (int nn = 0; nn < NF; ++nn) {
            int c = wc0 + nn * 16 + (lane & 15);
            float bv = bias[c];
            #pragma unroll
            for (int q = 0; q < 4; ++q) {
                int lrow = m0 + rloc + q;
                if (lrow < nrows) {
                    int grow = row0 + lrow;
                    float v = acc[m][nn][q] + bv;
                    if (RELU) v = fmaxf(v, 0.f);
                    if (F32OUT)
                        reinterpret_cast<float*>(outp)[(size_t)grow * BN + c] = v;
                    else
                        reinterpret_cast<ushort*>(outp)[(size_t)grow * BN + c] = f2bf(v);
                }
            }
        }
    }
}

// ---------------------------------------------------------------------------
// In-place log_softmax over rows of 16.
// ---------------------------------------------------------------------------
__global__ void log_softmax16(float* __restrict__ out) {
    int n = blockIdx.x * blockDim.x + threadIdx.x;
    if (n >= N_NODES) return;
    float4* p = reinterpret_cast<float4*>(out + (size_t)n * 16);
    float4 a = p[0], b = p[1], c = p[2], d = p[3];
    float m = a.x;
    m = fmaxf(m, a.y); m = fmaxf(m, a.z); m = fmaxf(m, a.w);
    m = fmaxf(m, b.x); m = fmaxf(m, b.y); m = fmaxf(m, b.z); m = fmaxf(m, b.w);
    m = fmaxf(m, c.x); m = fmaxf(m, c.y); m = fmaxf(m, c.z); m = fmaxf(m, c.w);
    m = fmaxf(m, d.x); m = fmaxf(m, d.y); m = fmaxf(m, d.z); m = fmaxf(m, d.w);
    float s = 0.f;
    s += expf(a.x - m) + expf(a.y - m) + expf(a.z - m) + expf(a.w - m);
    s += expf(b.x - m) + expf(b.y - m) + expf(b.z - m) + expf(b.w - m);
    s += expf(c.x - m) + expf(c.y - m) + expf(c.z - m) + expf(c.w - m);
    s += expf(d.x - m) + expf(d.y - m) + expf(d.z - m) + expf(d.w - m);
    float lse = m + logf(s);
    a.x -= lse; a.y -= lse; a.z -= lse; a.w -= lse;
    b.x -= lse; b.y -= lse; b.z -= lse; b.w -= lse;
    c.x -= lse; c.y -= lse; c.z -= lse; c.w -= lse;
    d.x -= lse; d.y -= lse; d.z -= lse; d.w -= lse;
    p[0] = a; p[1] = b; p[2] = c; p[3] = d;
}

// ---------------------------------------------------------------------------
extern "C" void kernel_launch(void* const* d_in, const int* in_sizes, int n_in,
                              void* d_out, int out_size, void* d_ws, size_t ws_size,
                              hipStream_t stream) {
    const float* x     = (const float*)d_in[0];
    const int*   ei    = (const int*)d_in[1];
    const int*   src   = ei;
    const int*   dst   = ei + N_EDGES;
    const float* ew    = (const float*)d_in[2];
    const int*   et    = (const int*)d_in[3];
    const float* W1    = (const float*)d_in[4];
    const float* root1 = (const float*)d_in[5];
    const float* b1    = (const float*)d_in[6];
    const float* W2    = (const float*)d_in[7];
    const float* root2 = (const float*)d_in[8];
    const float* b2    = (const float*)d_in[9];
    float* out = (float*)d_out;

    // workspace layout (~102 MiB)
    char* ws = (char*)d_ws;
    int*    counts = (int*)ws;                            //  2,000,000 B
    int*    offs   = (int*)(ws + 2000000);                //  2,000,000 B
    int*    tops   = (int*)(ws + 4000000);                //      4,096 B
    int2*   edges  = (int2*)(ws + 4004096);               // 12,800,000 B
    ushort* xh     = (ushort*)(ws + 16804096);            // 25,600,000 B
    ushort* h      = (ushort*)(ws + 42404096);            // 25,600,000 B
    ushort* Achunk = (ushort*)(ws + 68004096);            // 25088*1536 = 38,535,168 B (padded)
    ushort* Wt1    = (ushort*)(ws + 106539264);           //    196,608 B
    ushort* Wt2    = (ushort*)(ws + 106735872);           //     24,576 B

    // --- precision conversions ---
    cvt_feat<<<((N_NODES * 128 / 4) + 255) / 256, 256, 0, stream>>>(x, xh);
    cvt_wstack<<<dim3(3, 128), 256, 0, stream>>>(W1, root1, Wt1, 128);
    cvt_wstack<<<dim3(3, 16), 256, 0, stream>>>(W2, root2, Wt2, 16);

    // --- build (dst,rel)-bucketed CSR once ---
    hipMemsetAsync(counts, 0, (size_t)M_BUCKETS * sizeof(int), stream);
    count_edges<<<(N_EDGES + 255) / 256, 256, 0, stream>>>(dst, et, counts);
    scan1<<<SCAN_NB, 256, 0, stream>>>(counts, offs, tops);
    scan2<<<1, 512, 0, stream>>>(tops);
    scan3<<<(M_BUCKETS + 255) / 256, 256, 0, stream>>>(offs, tops);
    fill_edges<<<(N_EDGES + 255) / 256, 256, 0, stream>>>(src, dst, ew, et, counts, offs, edges);

    const int ggrid = (CHUNK + 4 - 1) / 4;        // 6250 gather blocks / chunk
    const int mgrid = (CHUNK + 127) / 128;        // 196 gemm blocks / chunk

    // --- layer 1: h = bf16(relu(A1 @ Wt1^T + b1)), A1 = [x | agg_r(x)] ---
    for (int c = 0; c < NCHUNK; ++c) {
        gather_all<<<ggrid, 256, 0, stream>>>(xh, edges, offs, Achunk, c * CHUNK);
        gemm768<128, true, false><<<mgrid, 256, 0, stream>>>(
            Achunk, Wt1, b1, h, c * CHUNK, CHUNK);
    }

    // --- layer 2: out = A2 @ Wt2^T + b2, A2 = [h | agg_r(h)] ---
    for (int c = 0; c < NCHUNK; ++c) {
        gather_all<<<ggrid, 256, 0, stream>>>(h, edges, offs, Achunk, c * CHUNK);
        gemm768<16, false, true><<<mgrid, 256, 0, stream>>>(
            Achunk, Wt2, b2, out, c * CHUNK, CHUNK);
    }

    log_softmax16<<<(N_NODES + 255) / 256, 256, 0, stream>>>(out);
}